// Round 11
// baseline (57.174 us; speedup 1.0000x reference)
//
#include <hip/hip_runtime.h>
#include <math.h>

// RelativePositionAttention on MI355X (gfx950)
//
// Algebraic simplifications (verified rounds 1-10, absmax <= 7.8e-3):
//  - U_ortho @ U_ortho^T == I -> skip QR projection entirely.
//  - RoPE factorizes: rotate Q,K by ABSOLUTE position (score invariant);
//    attention becomes plain masked sliding-window attention.
//  - GEMMs single-pass fp16 MFMA (K=512), fp32 accumulate; RoPE fused into
//    the QKV GEMM epilogue (incremental-angle rotation).
//
// Round 11: grid-balance retiling. mgemm0 128x128 (432 blocks, 1.69/CU, ~40%
// tail) -> 64x128 (864 blocks, 3.375/CU); mgemm1 64x128 (288, 1.125/CU, ~2x
// tail) -> 64x64 (576, 2.25/CU). Extra B re-reads absorbed by L2.

#define BB 2
#define HGRID 48
#define WGRID 48
#define NNODE (HGRID*WGRID)   // 2304
#define RAD 3
#define WSZ 49
#define DMODEL 512
#define NHEAD 8
#define SCALE 0.125f
#define MROWS (BB*NNODE)      // 4608
#define TPAD 141              // half2 units; rows<=140

typedef _Float16 f16;
typedef __attribute__((ext_vector_type(8))) _Float16 f16x8;
typedef __attribute__((ext_vector_type(2))) _Float16 h2;
typedef __attribute__((ext_vector_type(4))) float f32x4;

typedef union { f16x8 v8; h2 h[4]; } pack8;

#if __has_builtin(__builtin_amdgcn_fdot2)
__device__ __forceinline__ float fdot2(h2 a, h2 b, float c) {
    return __builtin_amdgcn_fdot2(a, b, c, false);
}
#else
__device__ __forceinline__ float fdot2(h2 a, h2 b, float c) {
    return fmaf((float)a.x, (float)b.x, fmaf((float)a.y, (float)b.y, c));
}
#endif

// ------- one-shot conversion: x -> fp16 row-major, weights -> fp16 B^T ------
__global__ void convert_all(const float* __restrict__ x,
                            const float* __restrict__ WQ, const float* __restrict__ WK,
                            const float* __restrict__ WV, const float* __restrict__ WO,
                            f16* __restrict__ x2, f16* __restrict__ Wall) {
    int id = blockIdx.x * 256 + threadIdx.x;         // (MROWS+2048)*64
    if (id < MROWS * 64) {
        int r = id >> 6, c8 = (id & 63) << 3;
        float4 a = *(const float4*)&x[(size_t)r * 512 + c8];
        float4 b = *(const float4*)&x[(size_t)r * 512 + c8 + 4];
        f16 o[8] = {(f16)a.x, (f16)a.y, (f16)a.z, (f16)a.w,
                    (f16)b.x, (f16)b.y, (f16)b.z, (f16)b.w};
        *(f16x8*)&x2[(size_t)r * 512 + c8] = *(f16x8*)o;
        return;
    }
    id -= MROWS * 64;
    if (id >= 2048 * 64) return;
    const int kb = ((id >> 6) & 63) << 3;            // k-block 0..504
    const int np = (id & 63) + ((id >> 12) << 6);    // lane -> consecutive np
    const float* S;
    int n;
    if (np < 1536) { int t = np >> 9; n = np & 511; S = (t == 0) ? WQ : (t == 1) ? WK : WV; }
    else           { n = np - 1536;  S = WO; }
    f16 o[8];
#pragma unroll
    for (int i = 0; i < 8; ++i) o[i] = (f16)S[(size_t)(kb + i) * 512 + n];
    *(f16x8*)&Wall[(size_t)np * 512 + kb] = *(f16x8*)o;
}

// ---------------- QKV GEMM: 64x128 tile, BK=64, K=512, 4 waves (32x64) -----
// Grid 864 (72 m x 12 n), bijective XCD swizzle. Epilogue: RoPE on Q,K via
// incremental rotation, fp16 stores (bh,n,d).
__global__ __launch_bounds__(256)
void mgemm0(const f16* __restrict__ A, const f16* __restrict__ Bt,
            f16* __restrict__ Qh, f16* __restrict__ Kh, f16* __restrict__ Vh,
            const float* __restrict__ freqs) {
    __shared__ f16 As[64 * 64];    // 8 KB
    __shared__ f16 Bs[128 * 64];   // 16 KB

    const int tid = threadIdx.x;
    const int l = tid & 63, wid = tid >> 6;

    const int bid = blockIdx.x;
    const int swz = (bid & 7) * 108 + (bid >> 3);    // 864 % 8 == 0
    const int m0 = (swz / 12) * 64;
    const int n0 = (swz % 12) * 128;

    const int wm = (wid >> 1) * 32, wn = (wid & 1) * 64;
    const int fr = l & 15, fk = l >> 4;
    const int srow = l >> 3, slot = l & 7;

    f32x4 acc[2][4];
#pragma unroll
    for (int m = 0; m < 2; ++m)
#pragma unroll
        for (int n = 0; n < 4; ++n) acc[m][n] = (f32x4){0.f, 0.f, 0.f, 0.f};

    for (int kt = 0; kt < 8; ++kt) {
        const int k0 = kt * 64;
#pragma unroll
        for (int j = 0; j < 2; ++j) {                // A: 64 rows (16/wave)
            const int r = wid * 16 + j * 8 + srow;
            const int cA = (slot ^ (r & 7)) * 8;     // pre-swizzled source
            const f16* gA = A + (size_t)(m0 + r) * 512 + k0 + cA;
            __builtin_amdgcn_global_load_lds(
                (const __attribute__((address_space(1))) unsigned int*)gA,
                (__attribute__((address_space(3))) unsigned int*)(As + wid * 1024 + j * 512),
                16, 0, 0);
        }
#pragma unroll
        for (int j = 0; j < 4; ++j) {                // B: 128 rows (32/wave)
            const int r = wid * 32 + j * 8 + srow;
            const int cA = (slot ^ (r & 7)) * 8;
            const f16* gB = Bt + (size_t)(n0 + r) * 512 + k0 + cA;
            __builtin_amdgcn_global_load_lds(
                (const __attribute__((address_space(1))) unsigned int*)gB,
                (__attribute__((address_space(3))) unsigned int*)(Bs + wid * 2048 + j * 512),
                16, 0, 0);
        }
        asm volatile("s_waitcnt vmcnt(0)" ::: "memory");
        __syncthreads();

        f16x8 af[2][2], bfr[4][2];
#pragma unroll
        for (int m = 0; m < 2; ++m) {
            const int row = wm + m * 16 + fr;
#pragma unroll
            for (int kk = 0; kk < 2; ++kk) {
                const int b = (kk * 64 + fk * 16) ^ ((row & 7) << 4);   // swz read
                af[m][kk] = *(const f16x8*)((const char*)As + row * 128 + b);
            }
        }
#pragma unroll
        for (int n = 0; n < 4; ++n) {
            const int row = wn + n * 16 + fr;
#pragma unroll
            for (int kk = 0; kk < 2; ++kk) {
                const int b = (kk * 64 + fk * 16) ^ ((row & 7) << 4);
                bfr[n][kk] = *(const f16x8*)((const char*)Bs + row * 128 + b);
            }
        }
#pragma unroll
        for (int kk = 0; kk < 2; ++kk)
#pragma unroll
            for (int m = 0; m < 2; ++m)
#pragma unroll
                for (int n = 0; n < 4; ++n)
                    acc[m][n] = __builtin_amdgcn_mfma_f32_16x16x32_f16(
                        af[m][kk], bfr[n][kk], acc[m][n], 0, 0, 0);
        __syncthreads();
    }

    // epilogue: C/D layout col = lane&15, row = (lane>>4)*4 + i  [m89]
#pragma unroll
    for (int nf = 0; nf < 4; ++nf) {
        const int ccol = n0 + wn + nf * 16 + fr;
        const int t = ccol >> 9;              // wave-uniform (128-tile in one 512)
        const int h = (ccol >> 6) & 7;
        const int d = ccol & 63;
        const int p = d >> 1;
        f16* Cp = (t == 0) ? Qh : (t == 1) ? Kh : Vh;
        if (t < 2) {
            const float fR = freqs[h * 64 + p];
            const float fC = freqs[h * 64 + 32 + p];
            const float sgn = (d & 1) ? 1.0f : -1.0f;
            float sF, cF;
            __sincosf(fC, &sF, &cF);
#pragma unroll
            for (int mf = 0; mf < 2; ++mf) {
                const int g0r = m0 + wm + mf * 16 + fk * 4;   // i=0 row
                const int b_ = g0r >= NNODE;                  // 64 | 2304
                const int nn0 = g0r - b_ * NNODE;
                const int rr = nn0 / WGRID;       // constant across i=0..3
                const int cc0 = nn0 - rr * WGRID; // 4-aligned -> no wrap
                float sn, cs;
                __sincosf((float)rr * fR + (float)cc0 * fC, &sn, &cs);
                const size_t base = ((size_t)((b_ * NHEAD + h) * NNODE + nn0)) * 64 + d;
#pragma unroll
                for (int i = 0; i < 4; ++i) {
                    float val = acc[mf][nf][i];
                    float part = __shfl_xor(val, 1);     // pair partner (d^1)
                    float outv = fmaf(sgn * part, sn, val * cs);
                    Cp[base + (size_t)i * 64] = (f16)outv;
                    float cs2 = cs * cF - sn * sF;       // theta += fC
                    sn = sn * cF + cs * sF;
                    cs = cs2;
                }
            }
        } else {
#pragma unroll
            for (int mf = 0; mf < 2; ++mf) {
#pragma unroll
                for (int i = 0; i < 4; ++i) {
                    const int grow = m0 + wm + mf * 16 + fk * 4 + i;
                    const int b_ = grow >= NNODE;
                    const int nn = grow - b_ * NNODE;
                    Cp[((size_t)((b_ * NHEAD + h) * NNODE + nn)) * 64 + d] =
                        (f16)acc[mf][nf][i];
                }
            }
        }
    }
}

// ---------------- W_O GEMM: 64x64 tile, BK=64, 4 waves (32x32) -------------
// Grid 576 (72 m x 8 n), bijective XCD swizzle; fp32 C row-major.
__global__ __launch_bounds__(256)
void mgemm1(const f16* __restrict__ A, const f16* __restrict__ Bt,
            float* __restrict__ Cf) {
    __shared__ f16 As[64 * 64];    // 8 KB
    __shared__ f16 Bs[64 * 64];    // 8 KB

    const int tid = threadIdx.x;
    const int l = tid & 63, wid = tid >> 6;

    const int bid = blockIdx.x;
    const int swz = (bid & 7) * 72 + (bid >> 3);     // 576 % 8 == 0
    const int m0 = (swz >> 3) * 64;                  // 72 m-tiles
    const int n0 = (swz & 7) * 64;

    const int wm = (wid >> 1) * 32, wn = (wid & 1) * 32;
    const int fr = l & 15, fk = l >> 4;
    const int srow = l >> 3, slot = l & 7;

    f32x4 acc[2][2];
#pragma unroll
    for (int m = 0; m < 2; ++m)
#pragma unroll
        for (int n = 0; n < 2; ++n) acc[m][n] = (f32x4){0.f, 0.f, 0.f, 0.f};

    for (int kt = 0; kt < 8; ++kt) {
        const int k0 = kt * 64;
#pragma unroll
        for (int j = 0; j < 2; ++j) {                // A: 64 rows (16/wave)
            const int r = wid * 16 + j * 8 + srow;
            const int cA = (slot ^ (r & 7)) * 8;
            const f16* gA = A + (size_t)(m0 + r) * 512 + k0 + cA;
            __builtin_amdgcn_global_load_lds(
                (const __attribute__((address_space(1))) unsigned int*)gA,
                (__attribute__((address_space(3))) unsigned int*)(As + wid * 1024 + j * 512),
                16, 0, 0);
            const f16* gB = Bt + (size_t)(n0 + r) * 512 + k0 + cA;
            __builtin_amdgcn_global_load_lds(
                (const __attribute__((address_space(1))) unsigned int*)gB,
                (__attribute__((address_space(3))) unsigned int*)(Bs + wid * 1024 + j * 512),
                16, 0, 0);
        }
        asm volatile("s_waitcnt vmcnt(0)" ::: "memory");
        __syncthreads();

        f16x8 af[2][2], bfr[2][2];
#pragma unroll
        for (int m = 0; m < 2; ++m) {
            const int row = wm + m * 16 + fr;
#pragma unroll
            for (int kk = 0; kk < 2; ++kk) {
                const int b = (kk * 64 + fk * 16) ^ ((row & 7) << 4);
                af[m][kk] = *(const f16x8*)((const char*)As + row * 128 + b);
            }
        }
#pragma unroll
        for (int n = 0; n < 2; ++n) {
            const int row = wn + n * 16 + fr;
#pragma unroll
            for (int kk = 0; kk < 2; ++kk) {
                const int b = (kk * 64 + fk * 16) ^ ((row & 7) << 4);
                bfr[n][kk] = *(const f16x8*)((const char*)Bs + row * 128 + b);
            }
        }
#pragma unroll
        for (int kk = 0; kk < 2; ++kk)
#pragma unroll
            for (int m = 0; m < 2; ++m)
#pragma unroll
                for (int n = 0; n < 2; ++n)
                    acc[m][n] = __builtin_amdgcn_mfma_f32_16x16x32_f16(
                        af[m][kk], bfr[n][kk], acc[m][n], 0, 0, 0);
        __syncthreads();
    }

#pragma unroll
    for (int nf = 0; nf < 2; ++nf) {
        const int ccol = n0 + wn + nf * 16 + fr;
#pragma unroll
        for (int mf = 0; mf < 2; ++mf) {
#pragma unroll
            for (int i = 0; i < 4; ++i) {
                const int grow = m0 + wm + mf * 16 + fk * 4 + i;
                Cf[(size_t)grow * 512 + ccol] = acc[mf][nf][i];
            }
        }
    }
}

// ---------------- attention v7: 18KB LDS, V prefetched into regs ----------
__global__ __launch_bounds__(256, 4)
void attn7(const f16* __restrict__ Qh, const f16* __restrict__ Kh,
           const f16* __restrict__ Vh, f16* __restrict__ out2) {
    __shared__ h2 T[32 * TPAD];

    const int tid = threadIdx.x;
    const int wid = tid >> 6, lane = tid & 63;
    const int qs = lane >> 3, wg = lane & 7;

    const int bid = blockIdx.x;
    const int t  = bid % 72, bh = bid / 72;
    const int tr = t % 12,   tc = t / 12;
    const int r0 = tr * 4,   c0 = tc * 8;
    const int h  = bh & 7,   b_ = bh >> 3;

    const int lr0 = max(0, r0 - 3), lr1 = min(HGRID - 1, r0 + 6);
    const int lc0 = max(0, c0 - 3), lc1 = min(WGRID - 1, c0 + 10);
    const int NR = lr1 - lr0 + 1, NC = lc1 - lc0 + 1;

    const f16* Kb = Kh + (size_t)bh * NNODE * 64;
    const f16* Vb = Vh + (size_t)bh * NNODE * 64;

    // ---- Q row into registers as half2 pairs ----
    const int rq = r0 + wid, cq = c0 + qs;
    const int nq = rq * WGRID + cq;
    const f16* qrow = Qh + ((size_t)bh * NNODE + nq) * 64;
    h2 q2[32];
#pragma unroll
    for (int j8 = 0; j8 < 8; ++j8) {
        pack8 v;
        v.v8 = *(const f16x8*)&qrow[j8 * 8];
#pragma unroll
        for (int k = 0; k < 4; ++k) q2[j8 * 4 + k] = v.h[k];
    }

    const int cnt = NR * NC * 8;                 // <= 1120

    // ---- issue V prefetch loads (in flight across K stage + score) ----
    f16x8 vpre[5];
#pragma unroll
    for (int s = 0; s < 5; ++s) {
        const int i = tid + s * 256;
        if (i < cnt) {
            const int row = i >> 3, p4 = i & 7;
            const int glr = row / NC, glc = row - glr * NC;
            const int n = (lr0 + glr) * WGRID + (lc0 + glc);
            vpre[s] = *(const f16x8*)&Vb[(size_t)n * 64 + p4 * 8];
        }
    }

    // ---- stage K (transposed half2) ----
    for (int i = tid; i < cnt; i += 256) {
        const int row = i >> 3, p4 = i & 7;
        const int glr = row / NC, glc = row - glr * NC;
        const int n = (lr0 + glr) * WGRID + (lc0 + glc);
        pack8 v;
        v.v8 = *(const f16x8*)&Kb[(size_t)n * 64 + p4 * 8];
#pragma unroll
        for (int j = 0; j < 4; ++j) T[(p4 * 4 + j) * TPAD + row] = v.h[j];
    }
    __syncthreads();

    // ---- score phase: lane (qs,wg) -> neighbors w = wg + 8k ----
    float sc[7], es[7];
    float mx = -1e30f;
#pragma unroll
    for (int k = 0; k < 7; ++k) {
        const int w = wg + 8 * k;
        sc[k] = -1e30f;
        if (w < WSZ) {
            const int dr = w / 7 - RAD, dc = w % 7 - RAD;
            const int nr = rq + dr, nc = cq + dc;
            const bool valid = ((unsigned)nr < (unsigned)HGRID) &&
                               ((unsigned)nc < (unsigned)WGRID);
            const int nrl = min(max(nr, lr0), lr1) - lr0;
            const int ncl = min(max(nc, lc0), lc1) - lc0;
            const int row = nrl * NC + ncl;
            float s = 0.0f;
#pragma unroll
            for (int j = 0; j < 32; ++j) s = fdot2(q2[j], T[j * TPAD + row], s);
            sc[k] = valid ? s * SCALE : -1e9f;
            mx = fmaxf(mx, sc[k]);
        }
    }
#pragma unroll
    for (int o = 1; o < 8; o <<= 1) mx = fmaxf(mx, __shfl_xor(mx, o));
    float sum = 0.0f;
#pragma unroll
    for (int k = 0; k < 7; ++k) {
        const int w = wg + 8 * k;
        es[k] = 0.0f;
        if (w < WSZ) { es[k] = __expf(sc[k] - mx); sum += es[k]; }
    }
#pragma unroll
    for (int o = 1; o < 8; o <<= 1) sum += __shfl_xor(sum, o);
    const float inv = 1.0f / sum;
    float esn[7];
#pragma unroll
    for (int k = 0; k < 7; ++k) esn[k] = es[k] * inv;

    __syncthreads();   // all waves done reading K

    // ---- write prefetched V into LDS (loads already landed) ----
#pragma unroll
    for (int s = 0; s < 5; ++s) {
        const int i = tid + s * 256;
        if (i < cnt) {
            const int row = i >> 3, p4 = i & 7;
            pack8 v; v.v8 = vpre[s];
#pragma unroll
            for (int j = 0; j < 4; ++j) T[(p4 * 4 + j) * TPAD + row] = v.h[j];
        }
    }
    __syncthreads();

    // ---- PV phase: lane (qs,dg) accumulates 8 dims ----
    const int dg = wg;
    float2 acc[4] = {{0, 0}, {0, 0}, {0, 0}, {0, 0}};
#pragma unroll
    for (int w = 0; w < WSZ; ++w) {
        const int dr = w / 7 - RAD, dc = w % 7 - RAD;
        const int nr = rq + dr, nc = cq + dc;
        const int nrl = min(max(nr, lr0), lr1) - lr0;
        const int ncl = min(max(nc, lc0), lc1) - lc0;
        const int row = nrl * NC + ncl;
        const float pw = __shfl(esn[w >> 3], (lane & 0x38) | (w & 7));
#pragma unroll
        for (int j = 0; j < 4; ++j) {
            h2 v2 = T[(dg * 4 + j) * TPAD + row];
            acc[j].x = fmaf(pw, (float)v2.x, acc[j].x);
            acc[j].y = fmaf(pw, (float)v2.y, acc[j].y);
        }
    }

    // ---- write fp16 row for the W_O GEMM ----
    f16 o[8] = {(f16)acc[0].x, (f16)acc[0].y, (f16)acc[1].x, (f16)acc[1].y,
                (f16)acc[2].x, (f16)acc[2].y, (f16)acc[3].x, (f16)acc[3].y};
    const size_t rowb = (size_t)(b_ * NNODE + nq) * 512 + h * 64 + dg * 8;
    *(f16x8*)&out2[rowb] = *(f16x8*)o;
}

extern "C" void kernel_launch(void* const* d_in, const int* in_sizes, int n_in,
                              void* d_out, int out_size, void* d_ws, size_t ws_size,
                              hipStream_t stream) {
    const float* x     = (const float*)d_in[0];
    const float* WQ    = (const float*)d_in[2];
    const float* WK    = (const float*)d_in[3];
    const float* WV    = (const float*)d_in[4];
    const float* WO    = (const float*)d_in[5];
    const float* freqs = (const float*)d_in[7];

    const size_t HN = (size_t)16 * NNODE * 64;      // per Q/K/V fp16 tensor
    f16* Qh   = (f16*)d_ws;
    f16* Kh   = Qh + HN;
    f16* Vh   = Kh + HN;
    f16* x2   = Vh + HN;                            // MROWS x 512
    f16* Wall = x2 + (size_t)MROWS * 512;           // 2048 x 512
    f16* Wo2  = Wall + (size_t)1536 * 512;

    convert_all<<<((MROWS + 2048) * 64 + 255) / 256, 256, 0, stream>>>(
        x, WQ, WK, WV, WO, x2, Wall);

    mgemm0<<<864, 256, 0, stream>>>(x2, Wall, Qh, Kh, Vh, freqs);

    attn7<<<16 * 72, 256, 0, stream>>>(Qh, Kh, Vh, x2);

    mgemm1<<<576, 256, 0, stream>>>(x2, Wo2, (float*)d_out);
}

// Round 12
// 56.319 us; speedup vs baseline: 1.0152x; 1.0152x over previous
//
#include <hip/hip_runtime.h>
#include <math.h>

// RelativePositionAttention on MI355X (gfx950)
//
// Algebraic simplifications (verified rounds 1-11, absmax <= 7.8e-3):
//  - U_ortho @ U_ortho^T == I -> skip QR projection entirely.
//  - RoPE factorizes: rotate Q,K by ABSOLUTE position (score invariant);
//    attention becomes plain masked sliding-window attention.
//  - GEMMs single-pass fp16 MFMA (K=512), fp32 accumulate; RoPE fused into
//    the QKV GEMM epilogue (incremental-angle rotation).
//
// Round 12: REVERT round-11 retiling (regressed; tail imbalance not binding).
// attn8: LDS layout transposed->row-major [row][64 f16] stride 144B so every
// access is ds_read/write_b128 (score 224->56 issues/lane, PV 196->49,
// staging transpose removed). Same bytes, ~4x fewer LDS issues, <=2-way
// conflicts (free).

#define BB 2
#define HGRID 48
#define WGRID 48
#define NNODE (HGRID*WGRID)   // 2304
#define RAD 3
#define WSZ 49
#define DMODEL 512
#define NHEAD 8
#define SCALE 0.125f
#define MROWS (BB*NNODE)      // 4608
#define TROW 72               // h2 units per row (144 B, 16B-aligned, 9 quads)

typedef _Float16 f16;
typedef __attribute__((ext_vector_type(8))) _Float16 f16x8;
typedef __attribute__((ext_vector_type(2))) _Float16 h2;
typedef __attribute__((ext_vector_type(4))) float f32x4;

typedef union { f16x8 v8; h2 h[4]; } pack8;

#if __has_builtin(__builtin_amdgcn_fdot2)
__device__ __forceinline__ float fdot2(h2 a, h2 b, float c) {
    return __builtin_amdgcn_fdot2(a, b, c, false);
}
#else
__device__ __forceinline__ float fdot2(h2 a, h2 b, float c) {
    return fmaf((float)a.x, (float)b.x, fmaf((float)a.y, (float)b.y, c));
}
#endif

// ------- one-shot conversion: x -> fp16 row-major, weights -> fp16 B^T ------
__global__ void convert_all(const float* __restrict__ x,
                            const float* __restrict__ WQ, const float* __restrict__ WK,
                            const float* __restrict__ WV, const float* __restrict__ WO,
                            f16* __restrict__ x2, f16* __restrict__ Wall) {
    int id = blockIdx.x * 256 + threadIdx.x;         // (MROWS+2048)*64
    if (id < MROWS * 64) {
        int r = id >> 6, c8 = (id & 63) << 3;
        float4 a = *(const float4*)&x[(size_t)r * 512 + c8];
        float4 b = *(const float4*)&x[(size_t)r * 512 + c8 + 4];
        f16 o[8] = {(f16)a.x, (f16)a.y, (f16)a.z, (f16)a.w,
                    (f16)b.x, (f16)b.y, (f16)b.z, (f16)b.w};
        *(f16x8*)&x2[(size_t)r * 512 + c8] = *(f16x8*)o;
        return;
    }
    id -= MROWS * 64;
    if (id >= 2048 * 64) return;
    const int kb = ((id >> 6) & 63) << 3;            // k-block 0..504
    const int np = (id & 63) + ((id >> 12) << 6);    // lane -> consecutive np
    const float* S;
    int n;
    if (np < 1536) { int t = np >> 9; n = np & 511; S = (t == 0) ? WQ : (t == 1) ? WK : WV; }
    else           { n = np - 1536;  S = WO; }
    f16 o[8];
#pragma unroll
    for (int i = 0; i < 8; ++i) o[i] = (f16)S[(size_t)(kb + i) * 512 + n];
    *(f16x8*)&Wall[(size_t)np * 512 + kb] = *(f16x8*)o;
}

// ---------------- QKV GEMM: 128x128 tile, BK=64, K=512, 4 waves ------------
// Grid 432 (12 x 36), bijective XCD swizzle. Epilogue: RoPE on Q,K via
// incremental rotation (theta steps by f_C), fp16 stores (bh,n,d).
__global__ __launch_bounds__(256)
void mgemm0(const f16* __restrict__ A, const f16* __restrict__ Bt,
            f16* __restrict__ Qh, f16* __restrict__ Kh, f16* __restrict__ Vh,
            const float* __restrict__ freqs) {
    __shared__ f16 As[128 * 64];
    __shared__ f16 Bs[128 * 64];

    const int tid = threadIdx.x;
    const int l = tid & 63, wid = tid >> 6;

    const int bid = blockIdx.x;
    const int swz = (bid & 7) * 54 + (bid >> 3);     // 432 % 8 == 0
    const int m0 = (swz / 12) * 128;
    const int n0 = (swz % 12) * 128;

    const int wm = (wid >> 1) * 64, wn = (wid & 1) * 64;
    const int fr = l & 15, fk = l >> 4;
    const int srow = l >> 3, slot = l & 7;

    f32x4 acc[4][4];
#pragma unroll
    for (int m = 0; m < 4; ++m)
#pragma unroll
        for (int n = 0; n < 4; ++n) acc[m][n] = (f32x4){0.f, 0.f, 0.f, 0.f};

    for (int kt = 0; kt < 8; ++kt) {
        const int k0 = kt * 64;
#pragma unroll
        for (int j = 0; j < 4; ++j) {
            const int r = wid * 32 + j * 8 + srow;
            const int cA = (slot ^ (r & 7)) * 8;       // pre-swizzled source
            const f16* gA = A + (size_t)(m0 + r) * 512 + k0 + cA;
            __builtin_amdgcn_global_load_lds(
                (const __attribute__((address_space(1))) unsigned int*)gA,
                (__attribute__((address_space(3))) unsigned int*)(As + wid * 2048 + j * 512),
                16, 0, 0);
            const f16* gB = Bt + (size_t)(n0 + r) * 512 + k0 + cA;
            __builtin_amdgcn_global_load_lds(
                (const __attribute__((address_space(1))) unsigned int*)gB,
                (__attribute__((address_space(3))) unsigned int*)(Bs + wid * 2048 + j * 512),
                16, 0, 0);
        }
        asm volatile("s_waitcnt vmcnt(0)" ::: "memory");
        __syncthreads();

        f16x8 af[4][2], bfr[4][2];
#pragma unroll
        for (int m = 0; m < 4; ++m) {
            const int row = wm + m * 16 + fr;
#pragma unroll
            for (int kk = 0; kk < 2; ++kk) {
                const int b = (kk * 64 + fk * 16) ^ ((row & 7) << 4);   // swz read
                af[m][kk] = *(const f16x8*)((const char*)As + row * 128 + b);
            }
        }
#pragma unroll
        for (int n = 0; n < 4; ++n) {
            const int row = wn + n * 16 + fr;
#pragma unroll
            for (int kk = 0; kk < 2; ++kk) {
                const int b = (kk * 64 + fk * 16) ^ ((row & 7) << 4);
                bfr[n][kk] = *(const f16x8*)((const char*)Bs + row * 128 + b);
            }
        }
#pragma unroll
        for (int kk = 0; kk < 2; ++kk)
#pragma unroll
            for (int m = 0; m < 4; ++m)
#pragma unroll
                for (int n = 0; n < 4; ++n)
                    acc[m][n] = __builtin_amdgcn_mfma_f32_16x16x32_f16(
                        af[m][kk], bfr[n][kk], acc[m][n], 0, 0, 0);
        __syncthreads();
    }

    // epilogue: C/D layout col = lane&15, row = (lane>>4)*4 + i  [m89]
#pragma unroll
    for (int nf = 0; nf < 4; ++nf) {
        const int ccol = n0 + wn + nf * 16 + fr;
        const int t = ccol >> 9;              // wave-uniform
        const int h = (ccol >> 6) & 7;
        const int d = ccol & 63;
        const int p = d >> 1;
        f16* Cp = (t == 0) ? Qh : (t == 1) ? Kh : Vh;
        if (t < 2) {
            const float fR = freqs[h * 64 + p];
            const float fC = freqs[h * 64 + 32 + p];
            const float sgn = (d & 1) ? 1.0f : -1.0f;
            float sF, cF;
            __sincosf(fC, &sF, &cF);
#pragma unroll
            for (int mf = 0; mf < 4; ++mf) {
                const int g0r = m0 + wm + mf * 16 + fk * 4;   // i=0 row
                const int b_ = g0r >= NNODE;
                const int nn0 = g0r - b_ * NNODE;
                const int rr = nn0 / WGRID;       // constant across i=0..3
                const int cc0 = nn0 - rr * WGRID; // 4-aligned -> no wrap
                float sn, cs;
                __sincosf((float)rr * fR + (float)cc0 * fC, &sn, &cs);
                const size_t base = ((size_t)((b_ * NHEAD + h) * NNODE + nn0)) * 64 + d;
#pragma unroll
                for (int i = 0; i < 4; ++i) {
                    float val = acc[mf][nf][i];
                    float part = __shfl_xor(val, 1);     // pair partner (d^1)
                    float outv = fmaf(sgn * part, sn, val * cs);
                    Cp[base + (size_t)i * 64] = (f16)outv;
                    float cs2 = cs * cF - sn * sF;       // theta += fC
                    sn = sn * cF + cs * sF;
                    cs = cs2;
                }
            }
        } else {
#pragma unroll
            for (int mf = 0; mf < 4; ++mf) {
#pragma unroll
                for (int i = 0; i < 4; ++i) {
                    const int grow = m0 + wm + mf * 16 + fk * 4 + i;
                    const int b_ = grow >= NNODE;
                    const int nn = grow - b_ * NNODE;
                    Cp[((size_t)((b_ * NHEAD + h) * NNODE + nn)) * 64 + d] =
                        (f16)acc[mf][nf][i];
                }
            }
        }
    }
}

// ---------------- W_O GEMM: 64x128 tile, BK=64, 4 waves (32x64 each) -------
// Grid 288 (4 x 72), bijective XCD swizzle; fp32 C row-major.
__global__ __launch_bounds__(256)
void mgemm1(const f16* __restrict__ A, const f16* __restrict__ Bt,
            float* __restrict__ Cf) {
    __shared__ f16 As[64 * 64];    // 8 KB
    __shared__ f16 Bs[128 * 64];   // 16 KB

    const int tid = threadIdx.x;
    const int l = tid & 63, wid = tid >> 6;

    const int bid = blockIdx.x;
    const int swz = (bid & 7) * 36 + (bid >> 3);     // 288 % 8 == 0
    const int m0 = (swz >> 2) * 64;                  // 72 m-tiles
    const int n0 = (swz & 3) * 128;

    const int wm = (wid >> 1) * 32, wn = (wid & 1) * 64;
    const int fr = l & 15, fk = l >> 4;
    const int srow = l >> 3, slot = l & 7;

    f32x4 acc[2][4];
#pragma unroll
    for (int m = 0; m < 2; ++m)
#pragma unroll
        for (int n = 0; n < 4; ++n) acc[m][n] = (f32x4){0.f, 0.f, 0.f, 0.f};

    for (int kt = 0; kt < 8; ++kt) {
        const int k0 = kt * 64;
#pragma unroll
        for (int j = 0; j < 2; ++j) {                // A: 64 rows (16/wave)
            const int r = wid * 16 + j * 8 + srow;
            const int cA = (slot ^ (r & 7)) * 8;
            const f16* gA = A + (size_t)(m0 + r) * 512 + k0 + cA;
            __builtin_amdgcn_global_load_lds(
                (const __attribute__((address_space(1))) unsigned int*)gA,
                (__attribute__((address_space(3))) unsigned int*)(As + wid * 1024 + j * 512),
                16, 0, 0);
        }
#pragma unroll
        for (int j = 0; j < 4; ++j) {                // B: 128 rows (32/wave)
            const int r = wid * 32 + j * 8 + srow;
            const int cA = (slot ^ (r & 7)) * 8;
            const f16* gB = Bt + (size_t)(n0 + r) * 512 + k0 + cA;
            __builtin_amdgcn_global_load_lds(
                (const __attribute__((address_space(1))) unsigned int*)gB,
                (__attribute__((address_space(3))) unsigned int*)(Bs + wid * 2048 + j * 512),
                16, 0, 0);
        }
        asm volatile("s_waitcnt vmcnt(0)" ::: "memory");
        __syncthreads();

        f16x8 af[2][2], bfr[4][2];
#pragma unroll
        for (int m = 0; m < 2; ++m) {
            const int row = wm + m * 16 + fr;
#pragma unroll
            for (int kk = 0; kk < 2; ++kk) {
                const int b = (kk * 64 + fk * 16) ^ ((row & 7) << 4);
                af[m][kk] = *(const f16x8*)((const char*)As + row * 128 + b);
            }
        }
#pragma unroll
        for (int n = 0; n < 4; ++n) {
            const int row = wn + n * 16 + fr;
#pragma unroll
            for (int kk = 0; kk < 2; ++kk) {
                const int b = (kk * 64 + fk * 16) ^ ((row & 7) << 4);
                bfr[n][kk] = *(const f16x8*)((const char*)Bs + row * 128 + b);
            }
        }
#pragma unroll
        for (int kk = 0; kk < 2; ++kk)
#pragma unroll
            for (int m = 0; m < 2; ++m)
#pragma unroll
                for (int n = 0; n < 4; ++n)
                    acc[m][n] = __builtin_amdgcn_mfma_f32_16x16x32_f16(
                        af[m][kk], bfr[n][kk], acc[m][n], 0, 0, 0);
        __syncthreads();
    }

#pragma unroll
    for (int nf = 0; nf < 4; ++nf) {
        const int ccol = n0 + wn + nf * 16 + fr;
#pragma unroll
        for (int mf = 0; mf < 2; ++mf) {
#pragma unroll
            for (int i = 0; i < 4; ++i) {
                const int grow = m0 + wm + mf * 16 + fk * 4 + i;
                Cf[(size_t)grow * 512 + ccol] = acc[mf][nf][i];
            }
        }
    }
}

// ---------------- attention v8: row-major LDS, all-b128 accesses ----------
// Block = 256 thr (4 waves), 4x8 query tile for one (b,h). T[row][64 f16],
// row stride 144B (9 bank-quads -> <=2-way conflicts). Staging is a straight
// 16B copy; score reads 8 x b128 per neighbor; PV reads 1 x b128 per w.
// V prefetched into regs before the K barrier (T14). ~19.7KB LDS, 4 blk/CU.
__global__ __launch_bounds__(256, 4)
void attn8(const f16* __restrict__ Qh, const f16* __restrict__ Kh,
           const f16* __restrict__ Vh, f16* __restrict__ out2) {
    __shared__ h2 T[140 * TROW];

    const int tid = threadIdx.x;
    const int wid = tid >> 6, lane = tid & 63;
    const int qs = lane >> 3, wg = lane & 7;

    const int bid = blockIdx.x;
    const int t  = bid % 72, bh = bid / 72;
    const int tr = t % 12,   tc = t / 12;
    const int r0 = tr * 4,   c0 = tc * 8;
    const int h  = bh & 7,   b_ = bh >> 3;

    const int lr0 = max(0, r0 - 3), lr1 = min(HGRID - 1, r0 + 6);
    const int lc0 = max(0, c0 - 3), lc1 = min(WGRID - 1, c0 + 10);
    const int NR = lr1 - lr0 + 1, NC = lc1 - lc0 + 1;

    const f16* Kb = Kh + (size_t)bh * NNODE * 64;
    const f16* Vb = Vh + (size_t)bh * NNODE * 64;

    // ---- Q row into registers as half2 pairs ----
    const int rq = r0 + wid, cq = c0 + qs;
    const int nq = rq * WGRID + cq;
    const f16* qrow = Qh + ((size_t)bh * NNODE + nq) * 64;
    h2 q2[32];
#pragma unroll
    for (int j8 = 0; j8 < 8; ++j8) {
        pack8 v;
        v.v8 = *(const f16x8*)&qrow[j8 * 8];
#pragma unroll
        for (int k = 0; k < 4; ++k) q2[j8 * 4 + k] = v.h[k];
    }

    const int cnt = NR * NC * 8;                 // 16B segments, <= 1120

    // ---- issue V prefetch loads (in flight across K stage + score) ----
    f16x8 vpre[5];
#pragma unroll
    for (int s = 0; s < 5; ++s) {
        const int i = tid + s * 256;
        if (i < cnt) {
            const int row = i >> 3, seg = i & 7;
            const int glr = row / NC, glc = row - glr * NC;
            const int n = (lr0 + glr) * WGRID + (lc0 + glc);
            vpre[s] = *(const f16x8*)&Vb[(size_t)n * 64 + seg * 8];
        }
    }

    // ---- stage K: straight 16B copy, row-major ----
    for (int i = tid; i < cnt; i += 256) {
        const int row = i >> 3, seg = i & 7;
        const int glr = row / NC, glc = row - glr * NC;
        const int n = (lr0 + glr) * WGRID + (lc0 + glc);
        *(f16x8*)&T[row * TROW + seg * 8] = *(const f16x8*)&Kb[(size_t)n * 64 + seg * 8];
    }
    __syncthreads();

    // ---- score phase: lane (qs,wg) -> neighbors w = wg + 8k ----
    float sc[7], es[7];
    float mx = -1e30f;
#pragma unroll
    for (int k = 0; k < 7; ++k) {
        const int w = wg + 8 * k;
        sc[k] = -1e30f;
        if (w < WSZ) {
            const int dr = w / 7 - RAD, dc = w % 7 - RAD;
            const int nr = rq + dr, nc = cq + dc;
            const bool valid = ((unsigned)nr < (unsigned)HGRID) &&
                               ((unsigned)nc < (unsigned)WGRID);
            const int nrl = min(max(nr, lr0), lr1) - lr0;
            const int ncl = min(max(nc, lc0), lc1) - lc0;
            const int row = nrl * NC + ncl;
            float s = 0.0f;
#pragma unroll
            for (int j8 = 0; j8 < 8; ++j8) {
                pack8 kv;
                kv.v8 = *(const f16x8*)&T[row * TROW + j8 * 8];
#pragma unroll
                for (int jj = 0; jj < 4; ++jj)
                    s = fdot2(q2[j8 * 4 + jj], kv.h[jj], s);
            }
            sc[k] = valid ? s * SCALE : -1e9f;
            mx = fmaxf(mx, sc[k]);
        }
    }
#pragma unroll
    for (int o = 1; o < 8; o <<= 1) mx = fmaxf(mx, __shfl_xor(mx, o));
    float sum = 0.0f;
#pragma unroll
    for (int k = 0; k < 7; ++k) {
        const int w = wg + 8 * k;
        es[k] = 0.0f;
        if (w < WSZ) { es[k] = __expf(sc[k] - mx); sum += es[k]; }
    }
#pragma unroll
    for (int o = 1; o < 8; o <<= 1) sum += __shfl_xor(sum, o);
    const float inv = 1.0f / sum;
    float esn[7];
#pragma unroll
    for (int k = 0; k < 7; ++k) esn[k] = es[k] * inv;

    __syncthreads();   // all waves done reading K

    // ---- write prefetched V into LDS (loads already landed) ----
#pragma unroll
    for (int s = 0; s < 5; ++s) {
        const int i = tid + s * 256;
        if (i < cnt) {
            const int row = i >> 3, seg = i & 7;
            *(f16x8*)&T[row * TROW + seg * 8] = vpre[s];
        }
    }
    __syncthreads();

    // ---- PV phase: lane (qs,dg) accumulates 8 dims, 1 b128 per w ----
    const int dg = wg;
    float2 acc[4] = {{0, 0}, {0, 0}, {0, 0}, {0, 0}};
#pragma unroll
    for (int w = 0; w < WSZ; ++w) {
        const int dr = w / 7 - RAD, dc = w % 7 - RAD;
        const int nr = rq + dr, nc = cq + dc;
        const int nrl = min(max(nr, lr0), lr1) - lr0;
        const int ncl = min(max(nc, lc0), lc1) - lc0;
        const int row = nrl * NC + ncl;
        const float pw = __shfl(esn[w >> 3], (lane & 0x38) | (w & 7));
        pack8 vv;
        vv.v8 = *(const f16x8*)&T[row * TROW + dg * 8];
#pragma unroll
        for (int j = 0; j < 4; ++j) {
            acc[j].x = fmaf(pw, (float)vv.h[j].x, acc[j].x);
            acc[j].y = fmaf(pw, (float)vv.h[j].y, acc[j].y);
        }
    }

    // ---- write fp16 row for the W_O GEMM ----
    f16 o[8] = {(f16)acc[0].x, (f16)acc[0].y, (f16)acc[1].x, (f16)acc[1].y,
                (f16)acc[2].x, (f16)acc[2].y, (f16)acc[3].x, (f16)acc[3].y};
    const size_t rowb = (size_t)(b_ * NNODE + nq) * 512 + h * 64 + dg * 8;
    *(f16x8*)&out2[rowb] = *(f16x8*)o;
}

extern "C" void kernel_launch(void* const* d_in, const int* in_sizes, int n_in,
                              void* d_out, int out_size, void* d_ws, size_t ws_size,
                              hipStream_t stream) {
    const float* x     = (const float*)d_in[0];
    const float* WQ    = (const float*)d_in[2];
    const float* WK    = (const float*)d_in[3];
    const float* WV    = (const float*)d_in[4];
    const float* WO    = (const float*)d_in[5];
    const float* freqs = (const float*)d_in[7];

    const size_t HN = (size_t)16 * NNODE * 64;      // per Q/K/V fp16 tensor
    f16* Qh   = (f16*)d_ws;
    f16* Kh   = Qh + HN;
    f16* Vh   = Kh + HN;
    f16* x2   = Vh + HN;                            // MROWS x 512
    f16* Wall = x2 + (size_t)MROWS * 512;           // 2048 x 512
    f16* Wo2  = Wall + (size_t)1536 * 512;

    convert_all<<<((MROWS + 2048) * 64 + 255) / 256, 256, 0, stream>>>(
        x, WQ, WK, WV, WO, x2, Wall);

    mgemm0<<<432, 256, 0, stream>>>(x2, Wall, Qh, Kh, Vh, freqs);

    attn8<<<16 * 72, 256, 0, stream>>>(Qh, Kh, Vh, x2);

    mgemm1<<<288, 256, 0, stream>>>(x2, Wo2, (float*)d_out);
}

// Round 13
// 55.075 us; speedup vs baseline: 1.0381x; 1.0226x over previous
//
#include <hip/hip_runtime.h>
#include <math.h>

// RelativePositionAttention on MI355X (gfx950)
//
// Algebraic simplifications (verified rounds 1-12, absmax <= 7.8e-3):
//  - U_ortho @ U_ortho^T == I -> skip QR projection entirely.
//  - RoPE factorizes: rotate Q,K by ABSOLUTE position (score invariant);
//    attention becomes plain masked sliding-window attention.
//  - GEMMs single-pass fp16 MFMA (K=512), fp32 accumulate; RoPE fused into
//    the QKV GEMM epilogue (incremental-angle rotation).
//
// Round 13: isolate round-11's confound - mgemm1 ONLY retiled to 64x64
// (grid 576, 2.25/CU vs 288's 1.125/CU two-round imbalance). mgemm0 stays
// 128x128/432 (best known), attn8 and convert_all unchanged.

#define BB 2
#define HGRID 48
#define WGRID 48
#define NNODE (HGRID*WGRID)   // 2304
#define RAD 3
#define WSZ 49
#define DMODEL 512
#define NHEAD 8
#define SCALE 0.125f
#define MROWS (BB*NNODE)      // 4608
#define TROW 72               // h2 units per row (144 B, 16B-aligned, 9 quads)

typedef _Float16 f16;
typedef __attribute__((ext_vector_type(8))) _Float16 f16x8;
typedef __attribute__((ext_vector_type(2))) _Float16 h2;
typedef __attribute__((ext_vector_type(4))) float f32x4;

typedef union { f16x8 v8; h2 h[4]; } pack8;

#if __has_builtin(__builtin_amdgcn_fdot2)
__device__ __forceinline__ float fdot2(h2 a, h2 b, float c) {
    return __builtin_amdgcn_fdot2(a, b, c, false);
}
#else
__device__ __forceinline__ float fdot2(h2 a, h2 b, float c) {
    return fmaf((float)a.x, (float)b.x, fmaf((float)a.y, (float)b.y, c));
}
#endif

// ------- one-shot conversion: x -> fp16 row-major, weights -> fp16 B^T ------
__global__ void convert_all(const float* __restrict__ x,
                            const float* __restrict__ WQ, const float* __restrict__ WK,
                            const float* __restrict__ WV, const float* __restrict__ WO,
                            f16* __restrict__ x2, f16* __restrict__ Wall) {
    int id = blockIdx.x * 256 + threadIdx.x;         // (MROWS+2048)*64
    if (id < MROWS * 64) {
        int r = id >> 6, c8 = (id & 63) << 3;
        float4 a = *(const float4*)&x[(size_t)r * 512 + c8];
        float4 b = *(const float4*)&x[(size_t)r * 512 + c8 + 4];
        f16 o[8] = {(f16)a.x, (f16)a.y, (f16)a.z, (f16)a.w,
                    (f16)b.x, (f16)b.y, (f16)b.z, (f16)b.w};
        *(f16x8*)&x2[(size_t)r * 512 + c8] = *(f16x8*)o;
        return;
    }
    id -= MROWS * 64;
    if (id >= 2048 * 64) return;
    const int kb = ((id >> 6) & 63) << 3;            // k-block 0..504
    const int np = (id & 63) + ((id >> 12) << 6);    // lane -> consecutive np
    const float* S;
    int n;
    if (np < 1536) { int t = np >> 9; n = np & 511; S = (t == 0) ? WQ : (t == 1) ? WK : WV; }
    else           { n = np - 1536;  S = WO; }
    f16 o[8];
#pragma unroll
    for (int i = 0; i < 8; ++i) o[i] = (f16)S[(size_t)(kb + i) * 512 + n];
    *(f16x8*)&Wall[(size_t)np * 512 + kb] = *(f16x8*)o;
}

// ---------------- QKV GEMM: 128x128 tile, BK=64, K=512, 4 waves ------------
// Grid 432 (12 x 36), bijective XCD swizzle. Epilogue: RoPE on Q,K via
// incremental rotation (theta steps by f_C), fp16 stores (bh,n,d).
__global__ __launch_bounds__(256)
void mgemm0(const f16* __restrict__ A, const f16* __restrict__ Bt,
            f16* __restrict__ Qh, f16* __restrict__ Kh, f16* __restrict__ Vh,
            const float* __restrict__ freqs) {
    __shared__ f16 As[128 * 64];
    __shared__ f16 Bs[128 * 64];

    const int tid = threadIdx.x;
    const int l = tid & 63, wid = tid >> 6;

    const int bid = blockIdx.x;
    const int swz = (bid & 7) * 54 + (bid >> 3);     // 432 % 8 == 0
    const int m0 = (swz / 12) * 128;
    const int n0 = (swz % 12) * 128;

    const int wm = (wid >> 1) * 64, wn = (wid & 1) * 64;
    const int fr = l & 15, fk = l >> 4;
    const int srow = l >> 3, slot = l & 7;

    f32x4 acc[4][4];
#pragma unroll
    for (int m = 0; m < 4; ++m)
#pragma unroll
        for (int n = 0; n < 4; ++n) acc[m][n] = (f32x4){0.f, 0.f, 0.f, 0.f};

    for (int kt = 0; kt < 8; ++kt) {
        const int k0 = kt * 64;
#pragma unroll
        for (int j = 0; j < 4; ++j) {
            const int r = wid * 32 + j * 8 + srow;
            const int cA = (slot ^ (r & 7)) * 8;       // pre-swizzled source
            const f16* gA = A + (size_t)(m0 + r) * 512 + k0 + cA;
            __builtin_amdgcn_global_load_lds(
                (const __attribute__((address_space(1))) unsigned int*)gA,
                (__attribute__((address_space(3))) unsigned int*)(As + wid * 2048 + j * 512),
                16, 0, 0);
            const f16* gB = Bt + (size_t)(n0 + r) * 512 + k0 + cA;
            __builtin_amdgcn_global_load_lds(
                (const __attribute__((address_space(1))) unsigned int*)gB,
                (__attribute__((address_space(3))) unsigned int*)(Bs + wid * 2048 + j * 512),
                16, 0, 0);
        }
        asm volatile("s_waitcnt vmcnt(0)" ::: "memory");
        __syncthreads();

        f16x8 af[4][2], bfr[4][2];
#pragma unroll
        for (int m = 0; m < 4; ++m) {
            const int row = wm + m * 16 + fr;
#pragma unroll
            for (int kk = 0; kk < 2; ++kk) {
                const int b = (kk * 64 + fk * 16) ^ ((row & 7) << 4);   // swz read
                af[m][kk] = *(const f16x8*)((const char*)As + row * 128 + b);
            }
        }
#pragma unroll
        for (int n = 0; n < 4; ++n) {
            const int row = wn + n * 16 + fr;
#pragma unroll
            for (int kk = 0; kk < 2; ++kk) {
                const int b = (kk * 64 + fk * 16) ^ ((row & 7) << 4);
                bfr[n][kk] = *(const f16x8*)((const char*)Bs + row * 128 + b);
            }
        }
#pragma unroll
        for (int kk = 0; kk < 2; ++kk)
#pragma unroll
            for (int m = 0; m < 4; ++m)
#pragma unroll
                for (int n = 0; n < 4; ++n)
                    acc[m][n] = __builtin_amdgcn_mfma_f32_16x16x32_f16(
                        af[m][kk], bfr[n][kk], acc[m][n], 0, 0, 0);
        __syncthreads();
    }

    // epilogue: C/D layout col = lane&15, row = (lane>>4)*4 + i  [m89]
#pragma unroll
    for (int nf = 0; nf < 4; ++nf) {
        const int ccol = n0 + wn + nf * 16 + fr;
        const int t = ccol >> 9;              // wave-uniform
        const int h = (ccol >> 6) & 7;
        const int d = ccol & 63;
        const int p = d >> 1;
        f16* Cp = (t == 0) ? Qh : (t == 1) ? Kh : Vh;
        if (t < 2) {
            const float fR = freqs[h * 64 + p];
            const float fC = freqs[h * 64 + 32 + p];
            const float sgn = (d & 1) ? 1.0f : -1.0f;
            float sF, cF;
            __sincosf(fC, &sF, &cF);
#pragma unroll
            for (int mf = 0; mf < 4; ++mf) {
                const int g0r = m0 + wm + mf * 16 + fk * 4;   // i=0 row
                const int b_ = g0r >= NNODE;
                const int nn0 = g0r - b_ * NNODE;
                const int rr = nn0 / WGRID;       // constant across i=0..3
                const int cc0 = nn0 - rr * WGRID; // 4-aligned -> no wrap
                float sn, cs;
                __sincosf((float)rr * fR + (float)cc0 * fC, &sn, &cs);
                const size_t base = ((size_t)((b_ * NHEAD + h) * NNODE + nn0)) * 64 + d;
#pragma unroll
                for (int i = 0; i < 4; ++i) {
                    float val = acc[mf][nf][i];
                    float part = __shfl_xor(val, 1);     // pair partner (d^1)
                    float outv = fmaf(sgn * part, sn, val * cs);
                    Cp[base + (size_t)i * 64] = (f16)outv;
                    float cs2 = cs * cF - sn * sF;       // theta += fC
                    sn = sn * cF + cs * sF;
                    cs = cs2;
                }
            }
        } else {
#pragma unroll
            for (int mf = 0; mf < 4; ++mf) {
#pragma unroll
                for (int i = 0; i < 4; ++i) {
                    const int grow = m0 + wm + mf * 16 + fk * 4 + i;
                    const int b_ = grow >= NNODE;
                    const int nn = grow - b_ * NNODE;
                    Cp[((size_t)((b_ * NHEAD + h) * NNODE + nn)) * 64 + d] =
                        (f16)acc[mf][nf][i];
                }
            }
        }
    }
}

// ---------------- W_O GEMM: 64x64 tile, BK=64, 4 waves (32x32) -------------
// Grid 576 (72 m x 8 n), bijective XCD swizzle; fp32 C row-major. 16KB LDS.
__global__ __launch_bounds__(256)
void mgemm1(const f16* __restrict__ A, const f16* __restrict__ Bt,
            float* __restrict__ Cf) {
    __shared__ f16 As[64 * 64];    // 8 KB
    __shared__ f16 Bs[64 * 64];    // 8 KB

    const int tid = threadIdx.x;
    const int l = tid & 63, wid = tid >> 6;

    const int bid = blockIdx.x;
    const int swz = (bid & 7) * 72 + (bid >> 3);     // 576 % 8 == 0
    const int m0 = (swz >> 3) * 64;                  // 72 m-tiles
    const int n0 = (swz & 7) * 64;

    const int wm = (wid >> 1) * 32, wn = (wid & 1) * 32;
    const int fr = l & 15, fk = l >> 4;
    const int srow = l >> 3, slot = l & 7;

    f32x4 acc[2][2];
#pragma unroll
    for (int m = 0; m < 2; ++m)
#pragma unroll
        for (int n = 0; n < 2; ++n) acc[m][n] = (f32x4){0.f, 0.f, 0.f, 0.f};

    for (int kt = 0; kt < 8; ++kt) {
        const int k0 = kt * 64;
#pragma unroll
        for (int j = 0; j < 2; ++j) {                // A,B: 64 rows each (16/wave)
            const int r = wid * 16 + j * 8 + srow;
            const int cA = (slot ^ (r & 7)) * 8;
            const f16* gA = A + (size_t)(m0 + r) * 512 + k0 + cA;
            __builtin_amdgcn_global_load_lds(
                (const __attribute__((address_space(1))) unsigned int*)gA,
                (__attribute__((address_space(3))) unsigned int*)(As + wid * 1024 + j * 512),
                16, 0, 0);
            const f16* gB = Bt + (size_t)(n0 + r) * 512 + k0 + cA;
            __builtin_amdgcn_global_load_lds(
                (const __attribute__((address_space(1))) unsigned int*)gB,
                (__attribute__((address_space(3))) unsigned int*)(Bs + wid * 1024 + j * 512),
                16, 0, 0);
        }
        asm volatile("s_waitcnt vmcnt(0)" ::: "memory");
        __syncthreads();

        f16x8 af[2][2], bfr[2][2];
#pragma unroll
        for (int m = 0; m < 2; ++m) {
            const int row = wm + m * 16 + fr;
#pragma unroll
            for (int kk = 0; kk < 2; ++kk) {
                const int b = (kk * 64 + fk * 16) ^ ((row & 7) << 4);
                af[m][kk] = *(const f16x8*)((const char*)As + row * 128 + b);
            }
        }
#pragma unroll
        for (int n = 0; n < 2; ++n) {
            const int row = wn + n * 16 + fr;
#pragma unroll
            for (int kk = 0; kk < 2; ++kk) {
                const int b = (kk * 64 + fk * 16) ^ ((row & 7) << 4);
                bfr[n][kk] = *(const f16x8*)((const char*)Bs + row * 128 + b);
            }
        }
#pragma unroll
        for (int kk = 0; kk < 2; ++kk)
#pragma unroll
            for (int m = 0; m < 2; ++m)
#pragma unroll
                for (int n = 0; n < 2; ++n)
                    acc[m][n] = __builtin_amdgcn_mfma_f32_16x16x32_f16(
                        af[m][kk], bfr[n][kk], acc[m][n], 0, 0, 0);
        __syncthreads();
    }

#pragma unroll
    for (int nf = 0; nf < 2; ++nf) {
        const int ccol = n0 + wn + nf * 16 + fr;
#pragma unroll
        for (int mf = 0; mf < 2; ++mf) {
#pragma unroll
            for (int i = 0; i < 4; ++i) {
                const int grow = m0 + wm + mf * 16 + fk * 4 + i;
                Cf[(size_t)grow * 512 + ccol] = acc[mf][nf][i];
            }
        }
    }
}

// ---------------- attention v8: row-major LDS, all-b128 accesses ----------
__global__ __launch_bounds__(256, 4)
void attn8(const f16* __restrict__ Qh, const f16* __restrict__ Kh,
           const f16* __restrict__ Vh, f16* __restrict__ out2) {
    __shared__ h2 T[140 * TROW];

    const int tid = threadIdx.x;
    const int wid = tid >> 6, lane = tid & 63;
    const int qs = lane >> 3, wg = lane & 7;

    const int bid = blockIdx.x;
    const int t  = bid % 72, bh = bid / 72;
    const int tr = t % 12,   tc = t / 12;
    const int r0 = tr * 4,   c0 = tc * 8;
    const int h  = bh & 7,   b_ = bh >> 3;

    const int lr0 = max(0, r0 - 3), lr1 = min(HGRID - 1, r0 + 6);
    const int lc0 = max(0, c0 - 3), lc1 = min(WGRID - 1, c0 + 10);
    const int NR = lr1 - lr0 + 1, NC = lc1 - lc0 + 1;

    const f16* Kb = Kh + (size_t)bh * NNODE * 64;
    const f16* Vb = Vh + (size_t)bh * NNODE * 64;

    // ---- Q row into registers as half2 pairs ----
    const int rq = r0 + wid, cq = c0 + qs;
    const int nq = rq * WGRID + cq;
    const f16* qrow = Qh + ((size_t)bh * NNODE + nq) * 64;
    h2 q2[32];
#pragma unroll
    for (int j8 = 0; j8 < 8; ++j8) {
        pack8 v;
        v.v8 = *(const f16x8*)&qrow[j8 * 8];
#pragma unroll
        for (int k = 0; k < 4; ++k) q2[j8 * 4 + k] = v.h[k];
    }

    const int cnt = NR * NC * 8;                 // 16B segments, <= 1120

    // ---- issue V prefetch loads (in flight across K stage + score) ----
    f16x8 vpre[5];
#pragma unroll
    for (int s = 0; s < 5; ++s) {
        const int i = tid + s * 256;
        if (i < cnt) {
            const int row = i >> 3, seg = i & 7;
            const int glr = row / NC, glc = row - glr * NC;
            const int n = (lr0 + glr) * WGRID + (lc0 + glc);
            vpre[s] = *(const f16x8*)&Vb[(size_t)n * 64 + seg * 8];
        }
    }

    // ---- stage K: straight 16B copy, row-major ----
    for (int i = tid; i < cnt; i += 256) {
        const int row = i >> 3, seg = i & 7;
        const int glr = row / NC, glc = row - glr * NC;
        const int n = (lr0 + glr) * WGRID + (lc0 + glc);
        *(f16x8*)&T[row * TROW + seg * 8] = *(const f16x8*)&Kb[(size_t)n * 64 + seg * 8];
    }
    __syncthreads();

    // ---- score phase: lane (qs,wg) -> neighbors w = wg + 8k ----
    float sc[7], es[7];
    float mx = -1e30f;
#pragma unroll
    for (int k = 0; k < 7; ++k) {
        const int w = wg + 8 * k;
        sc[k] = -1e30f;
        if (w < WSZ) {
            const int dr = w / 7 - RAD, dc = w % 7 - RAD;
            const int nr = rq + dr, nc = cq + dc;
            const bool valid = ((unsigned)nr < (unsigned)HGRID) &&
                               ((unsigned)nc < (unsigned)WGRID);
            const int nrl = min(max(nr, lr0), lr1) - lr0;
            const int ncl = min(max(nc, lc0), lc1) - lc0;
            const int row = nrl * NC + ncl;
            float s = 0.0f;
#pragma unroll
            for (int j8 = 0; j8 < 8; ++j8) {
                pack8 kv;
                kv.v8 = *(const f16x8*)&T[row * TROW + j8 * 8];
#pragma unroll
                for (int jj = 0; jj < 4; ++jj)
                    s = fdot2(q2[j8 * 4 + jj], kv.h[jj], s);
            }
            sc[k] = valid ? s * SCALE : -1e9f;
            mx = fmaxf(mx, sc[k]);
        }
    }
#pragma unroll
    for (int o = 1; o < 8; o <<= 1) mx = fmaxf(mx, __shfl_xor(mx, o));
    float sum = 0.0f;
#pragma unroll
    for (int k = 0; k < 7; ++k) {
        const int w = wg + 8 * k;
        es[k] = 0.0f;
        if (w < WSZ) { es[k] = __expf(sc[k] - mx); sum += es[k]; }
    }
#pragma unroll
    for (int o = 1; o < 8; o <<= 1) sum += __shfl_xor(sum, o);
    const float inv = 1.0f / sum;
    float esn[7];
#pragma unroll
    for (int k = 0; k < 7; ++k) esn[k] = es[k] * inv;

    __syncthreads();   // all waves done reading K

    // ---- write prefetched V into LDS (loads already landed) ----
#pragma unroll
    for (int s = 0; s < 5; ++s) {
        const int i = tid + s * 256;
        if (i < cnt) {
            const int row = i >> 3, seg = i & 7;
            *(f16x8*)&T[row * TROW + seg * 8] = vpre[s];
        }
    }
    __syncthreads();

    // ---- PV phase: lane (qs,dg) accumulates 8 dims, 1 b128 per w ----
    const int dg = wg;
    float2 acc[4] = {{0, 0}, {0, 0}, {0, 0}, {0, 0}};
#pragma unroll
    for (int w = 0; w < WSZ; ++w) {
        const int dr = w / 7 - RAD, dc = w % 7 - RAD;
        const int nr = rq + dr, nc = cq + dc;
        const int nrl = min(max(nr, lr0), lr1) - lr0;
        const int ncl = min(max(nc, lc0), lc1) - lc0;
        const int row = nrl * NC + ncl;
        const float pw = __shfl(esn[w >> 3], (lane & 0x38) | (w & 7));
        pack8 vv;
        vv.v8 = *(const f16x8*)&T[row * TROW + dg * 8];
#pragma unroll
        for (int j = 0; j < 4; ++j) {
            acc[j].x = fmaf(pw, (float)vv.h[j].x, acc[j].x);
            acc[j].y = fmaf(pw, (float)vv.h[j].y, acc[j].y);
        }
    }

    // ---- write fp16 row for the W_O GEMM ----
    f16 o[8] = {(f16)acc[0].x, (f16)acc[0].y, (f16)acc[1].x, (f16)acc[1].y,
                (f16)acc[2].x, (f16)acc[2].y, (f16)acc[3].x, (f16)acc[3].y};
    const size_t rowb = (size_t)(b_ * NNODE + nq) * 512 + h * 64 + dg * 8;
    *(f16x8*)&out2[rowb] = *(f16x8*)o;
}

extern "C" void kernel_launch(void* const* d_in, const int* in_sizes, int n_in,
                              void* d_out, int out_size, void* d_ws, size_t ws_size,
                              hipStream_t stream) {
    const float* x     = (const float*)d_in[0];
    const float* WQ    = (const float*)d_in[2];
    const float* WK    = (const float*)d_in[3];
    const float* WV    = (const float*)d_in[4];
    const float* WO    = (const float*)d_in[5];
    const float* freqs = (const float*)d_in[7];

    const size_t HN = (size_t)16 * NNODE * 64;      // per Q/K/V fp16 tensor
    f16* Qh   = (f16*)d_ws;
    f16* Kh   = Qh + HN;
    f16* Vh   = Kh + HN;
    f16* x2   = Vh + HN;                            // MROWS x 512
    f16* Wall = x2 + (size_t)MROWS * 512;           // 2048 x 512
    f16* Wo2  = Wall + (size_t)1536 * 512;

    convert_all<<<((MROWS + 2048) * 64 + 255) / 256, 256, 0, stream>>>(
        x, WQ, WK, WV, WO, x2, Wall);

    mgemm0<<<432, 256, 0, stream>>>(x2, Wall, Qh, Kh, Vh, freqs);

    attn8<<<16 * 72, 256, 0, stream>>>(Qh, Kh, Vh, x2);

    mgemm1<<<576, 256, 0, stream>>>(x2, Wo2, (float*)d_out);
}